// Round 9
// baseline (46.423 us; speedup 1.0000x reference)
//
#include <hip/hip_runtime.h>
#include <hip/hip_bf16.h>
#include <stdint.h>

// Problem constants
#define B_ROWS 16384
#define F_DIM  512
#define K_OUT  1000
#define K_PAD  1024

// GEMM tile (128x128, BK=64, 4 waves, ~64.5KB LDS -> 2 blocks/CU resident)
#define BM 128
#define BN 128
#define BK 64

typedef __attribute__((ext_vector_type(4))) float f32x4;
typedef __attribute__((ext_vector_type(8))) short short8;
typedef unsigned short u16;
typedef unsigned int   u32;

// Workspace layout (bytes)
#define OFF_WB   0                 // 1024*512*2 = 1048576
#define OFF_WSQ  1048576           // 1024*4     = 4096

__device__ __forceinline__ u16 f2bf(float f) {
  union { float f; u32 u; } v; v.f = f;
  u32 u = v.u;
  u32 r = (u + 0x7fffu + ((u >> 16) & 1u)) >> 16;   // RNE
  return (u16)r;
}

// packed f32x2 -> bf16x2 (RNE), D[15:0]=bf16(lo), D[31:16]=bf16(hi)
__device__ __forceinline__ u32 pkbf(float lo, float hi) {
  u32 d;
  asm("v_cvt_pk_bf16_f32 %0, %1, %2" : "=v"(d) : "v"(lo), "v"(hi));
  return d;
}

// ---- prep: cast W -> bf16 padded to K_PAD rows, row sums of squares ----
__global__ void prep_W(const float* __restrict__ W, u16* __restrict__ Wb,
                       float* __restrict__ wsq) {
  int w    = threadIdx.x >> 6;
  int lane = threadIdx.x & 63;
  int row  = blockIdx.x * 4 + w;
  uint4 p; p.x = p.y = p.z = p.w = 0u;
  float s = 0.f;
  if (row < K_OUT) {
    const float* src = W + (size_t)row * F_DIM + lane * 8;
    float4 v0 = *(const float4*)src;
    float4 v1 = *(const float4*)(src + 4);
    s = v0.x*v0.x + v0.y*v0.y + v0.z*v0.z + v0.w*v0.w
      + v1.x*v1.x + v1.y*v1.y + v1.z*v1.z + v1.w*v1.w;
    p.x = (u32)f2bf(v0.x) | ((u32)f2bf(v0.y) << 16);
    p.y = (u32)f2bf(v0.z) | ((u32)f2bf(v0.w) << 16);
    p.z = (u32)f2bf(v1.x) | ((u32)f2bf(v1.y) << 16);
    p.w = (u32)f2bf(v1.z) | ((u32)f2bf(v1.w) << 16);
  }
#pragma unroll
  for (int off = 32; off >= 1; off >>= 1) s += __shfl_xor(s, off);
  if (lane == 0) wsq[row] = s;
  *(uint4*)(Wb + (size_t)row * F_DIM + lane * 8) = p;
}

// ---- async global -> LDS, 16B per lane (dest is wave-uniform base + lane*16) ----
__device__ __forceinline__ void gload_lds16(const void* g, void* l) {
  __builtin_amdgcn_global_load_lds(
      (const __attribute__((address_space(1))) void*)g,
      (__attribute__((address_space(3))) void*)l,
      16, 0, 0);
}

// ---- fused GEMM: A reg-staged from fp32 D (dsq fused), B gload_lds from Wb ----
// out[m][n] = gamma[n] * (2*cross[m][n] - dsq[m] - wsq[n]), n < K_OUT
//
// LDS (66048 B -> 2 blocks/CU):
//   bufA0 [0,16K)  bufA1 [16K,32K)  bufB0 [32K,48K)  bufB1 [48K,64K)
//   dsq_s [64K, 64K+512)  |  epilogue chunk [64][132]f32 reuses [0, 33.8K)
// Tiles are [128 rows][64 k] bf16; row = 128B = 8 slots of 16B; k-slot s of
// row r stored at slot (s ^ (r&7)). B's staging pre-swizzles the global source
// (rule #21); A's reg-staging writes the swizzled slot directly.
//
// Per K-tile body t (2 barriers; counted vmcnt; no vmcnt(0) in loop):
//   issue 8 A float4 loads (t+1 -> regs) + 4 B gload_lds (t+1 -> bufB^1)
//   sched_barrier  -- pins the issue cluster at the top (R6's sinking fix)
//   s_waitcnt vmcnt(12): retires tile-t's 4 B loads (12 newer remain); barrier
//   16 ds_read_b128 frags; setprio(1); 32 MFMA; setprio(0)
//   sched_barrier; if t<7: cvt(A regs)+dsq-fma+8 ds_write_b64 -> bufA^1
//   lgkmcnt(0); sched_barrier; barrier
// t=7 issues phantom tile-8 loads (kbn wraps to 0; B->bufB0 unused, A regs
// dead) to keep the vmcnt ledger uniform; WRITE is skipped so dsq stays exact.

#define LOAD_A(kb)                                                             \
  _Pragma("unroll") for (int i = 0; i < 8; ++i) {                              \
    int r = w * 32 + i * 4 + r4;                                               \
    la[i] = *(const float4*)(Dg + (size_t)r * F_DIM + (kb) + gq * 4);          \
  }

#define WRITE_A(dstA)                                                          \
  _Pragma("unroll") for (int i = 0; i < 8; ++i) {                              \
    int r = w * 32 + i * 4 + r4;                                               \
    pa[i] += la[i].x*la[i].x + la[i].y*la[i].y                                 \
           + la[i].z*la[i].z + la[i].w*la[i].w;                                \
    uint2 q2; q2.x = pkbf(la[i].x, la[i].y); q2.y = pkbf(la[i].z, la[i].w);    \
    *(uint2*)((dstA) + r * 128 + (((gq >> 1) ^ (r & 7)) << 4) + (gq & 1) * 8)  \
        = q2;                                                                  \
  }

#define STAGE_B(q)                                                             \
  _Pragma("unroll") for (int j = 0; j < 2; ++j) {                              \
    int rb = (q) * 32 + j * 64 + w * 8;                                        \
    int r  = rb + (lane >> 3);                                                 \
    int sc = s8 ^ (r & 7);                                                     \
    gload_lds16(Bg + (size_t)r * F_DIM + kbn + sc * 8, sBn + rb * 128);        \
  }

__global__ __launch_bounds__(256, 2) void gemm_eps(
    const float* __restrict__ D,     // [B_ROWS][F_DIM] fp32
    const u16*   __restrict__ Bw,    // [K_PAD][F_DIM]  bf16 (padded rows 0)
    const float* __restrict__ wsq,   // [K_PAD]
    const float* __restrict__ gamma, // [K_OUT]
    float* __restrict__ out) {       // [B_ROWS][K_OUT]
  __shared__ __align__(16) char lds[66048];
  float* dsq_s = (float*)(lds + 65536);   // [128]

  const int tid  = threadIdx.x;
  const int w    = tid >> 6;     // wave 0..3
  const int lane = tid & 63;
  const int lr   = lane & 15;
  const int lk4  = lane >> 4;
  const int wm   = w >> 1;       // 2 M-waves
  const int wn   = w & 1;        // 2 N-waves
  const int gq   = lane & 15;    // A-staging granule (16B of fp32 = 4 floats)
  const int r4   = lane >> 4;    // A-staging row-within-4
  const int s8   = lane & 7;     // B-staging 16B slot

  // XCD-aware swizzle (grid=1024, %8==0 -> bijective). Consecutive wg on one
  // XCD share the A-panel (same mt) -> fp32 D panel fetched from HBM once/XCD.
  const int bid = blockIdx.x;
  const int wg  = (bid & 7) * 128 + (bid >> 3);
  const int mt  = wg >> 3;       // 128 M-tiles
  const int nt  = wg & 7;        // 8 N-tiles
  const int m0  = mt * BM;
  const int n0  = nt * BN;

  const float* Dg = D  + (size_t)m0 * F_DIM;
  const u16*   Bg = Bw + (size_t)n0 * F_DIM;

  f32x4 acc[4][4];
#pragma unroll
  for (int i = 0; i < 4; ++i)
#pragma unroll
    for (int j = 0; j < 4; ++j) acc[i][j] = (f32x4){0.f, 0.f, 0.f, 0.f};
  float  pa[8] = {0.f, 0.f, 0.f, 0.f, 0.f, 0.f, 0.f, 0.f};
  float4 la[8];

  // epilogue col-operands prefetched now (latency hides under the K-loop)
  float g_[4], wq_[4];
#pragma unroll
  for (int ni = 0; ni < 4; ++ni) {
    int col = n0 + wn * 64 + ni * 16 + lr;
    g_[ni]  = (col < K_OUT) ? gamma[col] : 0.f;
    wq_[ni] = wsq[col & (K_PAD - 1)];
  }

  // prologue: stage K-tile 0 (A via regs+cvt, B via gload_lds)
  {
    char* sBn = lds + 32768;
    const int kbn = 0;
    LOAD_A(0)
    STAGE_B(0) STAGE_B(1)
    WRITE_A(lds)   // compiler auto-waits vmcnt on la; B(0) stays in flight
    asm volatile("s_waitcnt lgkmcnt(0)" ::: "memory");
    __builtin_amdgcn_sched_barrier(0);
  }

#pragma unroll 2
  for (int t = 0; t < 8; ++t) {
    const char* sAc = lds + (t & 1) * 16384;
    const char* sBc = lds + 32768 + (t & 1) * 16384;
    char* sAn = lds + ((t + 1) & 1) * 16384;
    char* sBn = lds + 32768 + ((t + 1) & 1) * 16384;
    const int kbn = ((t + 1) & 7) * BK;   // t=7 phantom wraps to k=0

    LOAD_A(kbn)
    STAGE_B(0) STAGE_B(1)
    __builtin_amdgcn_sched_barrier(0);    // pin issue cluster at top

    asm volatile("s_waitcnt vmcnt(12)" ::: "memory");  // tile t's B resident
    __builtin_amdgcn_s_barrier();

    short8 a[2][4], b[2][4];
#pragma unroll
    for (int kk = 0; kk < 2; ++kk)
#pragma unroll
      for (int mi = 0; mi < 4; ++mi) {
        int rA = wm * 64 + mi * 16 + lr;
        a[kk][mi] = *(const short8*)(sAc + rA * 128 +
                                     ((((kk << 2) + lk4) ^ (rA & 7)) << 4));
        int rB = wn * 64 + mi * 16 + lr;
        b[kk][mi] = *(const short8*)(sBc + rB * 128 +
                                     ((((kk << 2) + lk4) ^ (rB & 7)) << 4));
      }

    __builtin_amdgcn_s_setprio(1);
#pragma unroll
    for (int kk = 0; kk < 2; ++kk)
#pragma unroll
      for (int mi = 0; mi < 4; ++mi)
#pragma unroll
        for (int ni = 0; ni < 4; ++ni)
          acc[mi][ni] = __builtin_amdgcn_mfma_f32_16x16x32_bf16(
              a[kk][mi], b[kk][ni], acc[mi][ni], 0, 0, 0);
    __builtin_amdgcn_s_setprio(0);
    __builtin_amdgcn_sched_barrier(0);    // keep cvt/ds_write below the MFMAs

    if (t < 7) { WRITE_A(sAn) }           // publish A(t+1); skip phantom t=7
    asm volatile("s_waitcnt lgkmcnt(0)" ::: "memory");
    __builtin_amdgcn_sched_barrier(0);
    __builtin_amdgcn_s_barrier();         // buf reads done before next overwrite
  }

  // ---- dsq: reduce thread partials across the 16 granule lanes -> LDS ----
#pragma unroll
  for (int i = 0; i < 8; ++i) {
    float s = pa[i];
    s += __shfl_xor(s, 1); s += __shfl_xor(s, 2);
    s += __shfl_xor(s, 4); s += __shfl_xor(s, 8);
    if (gq == 0) dsq_s[w * 32 + i * 4 + r4] = s;
  }
  __syncthreads();   // drains phantom loads (vmcnt 0) + dsq_s writes visible

  float4 dl[4];
#pragma unroll
  for (int mi = 0; mi < 4; ++mi)
    dl[mi] = *(const float4*)&dsq_s[wm * 64 + mi * 16 + lk4 * 4];

  // ---- fused epilogue via LDS transpose (coalesced 128B row stores) ----
  float* ch = (float*)lds;       // chunk [64][132] f32 (pad 132 -> <=2-way banks)
  const int rl = tid >> 3;
  const int cb = (tid & 7) << 2;
#pragma unroll
  for (int c = 0; c < 2; ++c) {
    __syncthreads();   // previous chunk fully read
    if (wm == c) {
#pragma unroll
      for (int mi = 0; mi < 4; ++mi) {
        const int row_l = mi * 16 + lk4 * 4;
#pragma unroll
        for (int j = 0; j < 4; ++j) {
          float dq = (j == 0) ? dl[mi].x : (j == 1) ? dl[mi].y
                   : (j == 2) ? dl[mi].z : dl[mi].w;
#pragma unroll
          for (int ni = 0; ni < 4; ++ni) {
            ch[(row_l + j) * 132 + wn * 64 + ni * 16 + lr] =
                g_[ni] * (2.f * acc[mi][ni][j] - dq - wq_[ni]);
          }
        }
      }
    }
    __syncthreads();   // chunk visible to all waves
#pragma unroll
    for (int half = 0; half < 2; ++half) {
#pragma unroll
      for (int s = 0; s < 4; ++s) {
        int row = half * 32 + rl;
        int col = cb + s * 32;
        if (n0 + col < K_OUT) {
          float4 v = *(const float4*)&ch[row * 132 + col];
          *(float4*)&out[(size_t)(m0 + c * 64 + row) * K_OUT + n0 + col] = v;
        }
      }
    }
  }
}

extern "C" void kernel_launch(void* const* d_in, const int* in_sizes, int n_in,
                              void* d_out, int out_size, void* d_ws, size_t ws_size,
                              hipStream_t stream) {
  const float* D     = (const float*)d_in[0];
  const float* W     = (const float*)d_in[1];
  const float* gamma = (const float*)d_in[2];
  float* out = (float*)d_out;
  char*  ws  = (char*)d_ws;

  u16*   Wb  = (u16*)(ws + OFF_WB);
  float* wsq = (float*)(ws + OFF_WSQ);

  prep_W<<<K_PAD / 4, 256, 0, stream>>>(W, Wb, wsq);

  // grid = (16384/128) * (1024/128) = 1024 blocks, 2 resident/CU
  gemm_eps<<<(B_ROWS / BM) * (K_PAD / BN), 256, 0, stream>>>(
      D, Wb, wsq, gamma, out);
}